// Round 1
// baseline (39.145 us; speedup 1.0000x reference)
//
#include <hip/hip_runtime.h>
#include <math.h>

// EigenMatrixGenerator: N=40 grid, state S=4800.
// Analytic collapse: A = Re(P diag(L) P^H) with P made of diagonal blocks
//   [I I I; 0 D(v2) D(v3); 0 D(v2) D(v3)], v3 = -conj(v2), lam3 = conj(lam2).
// => A[0,1]=A[0,2]=A[1,0]=A[2,0]=0 blocks (z - conj z, real part 0)
//    A[0,0](i)           = lam1 + 2*real_part
//    A[1,1]=A[1,2]=A[2,1]=A[2,2](i) = 2*|v2|^2*real_part
// W = (A - 0.97 I)/0.03. Outputs: A (23.04M), W (23.04M), c_pos (1600), k (1600).

constexpr int   GN  = 40;
constexpr int   G   = GN * GN;          // 1600
constexpr long long S  = 3LL * G;       // 4800
constexpr long long SS = S * S;         // 23,040,000

__global__ void zero_fill_kernel(float4* __restrict__ out, long long n4) {
    long long i      = (long long)blockIdx.x * blockDim.x + threadIdx.x;
    long long stride = (long long)gridDim.x * blockDim.x;
    const float4 z = make_float4(0.f, 0.f, 0.f, 0.f);
    for (; i < n4; i += stride) out[i] = z;
}

__device__ __forceinline__ float softplus_f(float x) {
    // jax.nn.softplus = logaddexp(x, 0) = max(x,0) + log1p(exp(-|x|))
    return fmaxf(x, 0.0f) + log1pf(expf(-fabsf(x)));
}

__global__ void eigen_scatter_kernel(const float* __restrict__ c,
                                     const float* __restrict__ k,
                                     const float* __restrict__ kp,
                                     float* __restrict__ out) {
    int i = blockIdx.x * blockDim.x + threadIdx.x;
    if (i >= G) return;

    float cv  = c[i];
    float kv  = k[i];
    float kpv = kp[i];

    float c_pos = softplus_f(cv);
    float k_x   = softplus_f(kv);
    float kp_p  = softplus_f(kpv);

    const float xi = 1.57079632679489662f;  // float32(pi/2), DT = 1

    float okx  = 1.0f + k_x;                 // 1 + DT*k_x
    float okp  = 1.0f + kp_p;                // 1 + DT*kp_p
    float lam1 = 1.0f / okx;
    float rp   = 0.5f * (1.0f / okp + lam1); // real_part = Re(lam2)
    float im   = c_pos * xi / sqrtf(okp * okx);  // Im(lam2)

    // alpha = lam2 - lam1 + 1e-6 ; v2 = i*beta*xi/alpha, beta = DT/(1+k_x) = lam1
    float ar   = rp - lam1 + 1e-6f;
    float bx   = lam1 * xi;                  // beta * xi
    float den  = ar * ar + im * im;          // |alpha|^2
    float v2sq = bx * bx / den;              // |v2|^2

    float d1 = lam1 + 2.0f * rp;             // A[0,0] diagonal value
    float d2 = 2.0f * v2sq * rp;             // A[1,1]=A[1,2]=A[2,1]=A[2,2] value

    float* __restrict__ A = out;
    float* __restrict__ W = out + SS;

    long long di0 = (long long)i            * (S + 1);
    long long di1 = (long long)(G + i)      * (S + 1);
    long long di2 = (long long)(2 * G + i)  * (S + 1);

    A[di0]     = d1;
    A[di1]     = d2;
    A[di1 + G] = d2;
    A[di2 - G] = d2;
    A[di2]     = d2;

    const float LEAKY = 0.03f;
    const float OML   = 0.97f;  // 1 - LEAKY
    W[di0]     = (d1 - OML) / LEAKY;
    W[di1]     = (d2 - OML) / LEAKY;
    W[di1 + G] = d2 / LEAKY;
    W[di2 - G] = d2 / LEAKY;
    W[di2]     = (d2 - OML) / LEAKY;

    // outputs 2 and 3: c_pos (40x40) and k passthrough (40x40)
    out[2 * SS + i]     = c_pos;
    out[2 * SS + G + i] = kv;
}

extern "C" void kernel_launch(void* const* d_in, const int* in_sizes, int n_in,
                              void* d_out, int out_size, void* d_ws, size_t ws_size,
                              hipStream_t stream) {
    const float* c  = (const float*)d_in[0];
    const float* k  = (const float*)d_in[1];
    const float* kp = (const float*)d_in[2];
    float* out = (float*)d_out;

    // 1) zero the A and W regions (2*SS floats, divisible by 4)
    long long n4 = (2LL * SS) / 4;          // 11,520,000 float4 stores
    zero_fill_kernel<<<2048, 256, 0, stream>>>((float4*)out, n4);

    // 2) compute + scatter the 8000 nonzeros of A, 8000 of W, c_pos, k
    eigen_scatter_kernel<<<(G + 255) / 256, 256, 0, stream>>>(c, k, kp, out);
}

// Round 2
// 32.876 us; speedup vs baseline: 1.1907x; 1.1907x over previous
//
#include <hip/hip_runtime.h>
#include <math.h>

// EigenMatrixGenerator: N=40 grid, state S=4800.
// Analytic collapse: A = Re(P diag(L) P^H) with P made of diagonal blocks
//   [I I I; 0 D(v2) D(v3); 0 D(v2) D(v3)], v3 = -conj(v2), lam3 = conj(lam2).
// => A[0,1]=A[0,2]=A[1,0]=A[2,0]=0 blocks (z - conj(z) is purely imaginary)
//    A[0,0](i)                       = lam1 + 2*real_part            (= d1)
//    A[1,1]=A[1,2]=A[2,1]=A[2,2](i)  = 2*|v2|^2*real_part            (= d2)
// W = (A - 0.97 I)/0.03.
// Outputs: A (23.04M f32), W (23.04M), c_pos (1600), k (1600) = 184.3 MB.
// Cost is pure HBM write BW; single fused kernel: one block per row,
// coalesced float4 streaming with the <=2 nonzeros patched inline.

constexpr int       GN = 40;
constexpr int       G  = GN * GN;        // 1600
constexpr int       S  = 3 * G;          // 4800
constexpr long long SS = (long long)S * S;  // 23,040,000
constexpr int       ROW4 = S / 4;        // 1200 float4 per row

__device__ __forceinline__ float softplus_f(float x) {
    // jax.nn.softplus = max(x,0) + log1p(exp(-|x|))
    return fmaxf(x, 0.0f) + log1pf(expf(-fabsf(x)));
}

__global__ __launch_bounds__(256) void eigen_rows_kernel(
        const float* __restrict__ c,
        const float* __restrict__ k,
        const float* __restrict__ kp,
        float* __restrict__ out) {
    int r = blockIdx.x;                  // 0..9599 = rows of [A; W], 9600 = tail

    if (r >= 2 * S) {
        // tail: c_pos (40x40) then k passthrough (40x40)
        for (int i = threadIdx.x; i < G; i += 256) {
            out[2 * SS + i]     = softplus_f(c[i]);
            out[2 * SS + G + i] = k[i];
        }
        return;
    }

    bool isW = r >= S;
    int  rr  = isW ? r - S : r;          // row within the 4800x4800 matrix
    int  b   = rr / G;                   // block row 0,1,2 (wave-uniform)
    int  g   = rr % G;                   // grid index

    // per-index eigen values (wave-uniform scalar math; inputs L2-resident)
    float c_pos = softplus_f(c[g]);
    float k_x   = softplus_f(k[g]);
    float kp_p  = softplus_f(kp[g]);

    const float xi = 1.57079632679489662f;   // float32(pi/2), DT = 1
    float okx  = 1.0f + k_x;
    float okp  = 1.0f + kp_p;
    float lam1 = 1.0f / okx;
    float rp   = 0.5f * (1.0f / okp + lam1);     // Re(lam2)
    float im   = c_pos * xi / sqrtf(okp * okx);  // Im(lam2)
    float ar   = rp - lam1 + 1e-6f;              // Re(alpha)
    float bx   = lam1 * xi;                      // beta*xi (beta = lam1)
    float v2sq = bx * bx / (ar * ar + im * im);  // |v2|^2

    float d1 = lam1 + 2.0f * rp;                 // A[0,0] diag
    float d2 = 2.0f * v2sq * rp;                 // A[1,1]=A[1,2]=A[2,1]=A[2,2]

    const float INV_L = 1.0f / 0.03f;
    const float OML   = 0.97f;

    // nonzero columns c1 <= c2 and their values for this row
    int   c1, c2;
    float v1, v2v;
    if (b == 0) {
        c1 = g;      v1 = isW ? (d1 - OML) * INV_L : d1;
        c2 = -1;     v2v = 0.0f;
    } else if (b == 1) {
        c1 = G + g;      v1  = isW ? (d2 - OML) * INV_L : d2;   // diagonal
        c2 = 2 * G + g;  v2v = isW ? d2 * INV_L : d2;           // off-diag
    } else {
        c1 = G + g;      v1  = isW ? d2 * INV_L : d2;           // off-diag
        c2 = 2 * G + g;  v2v = isW ? (d2 - OML) * INV_L : d2;   // diagonal
    }

    float4* __restrict__ row4 = (float4*)out + (long long)r * ROW4;
    for (int i4 = threadIdx.x; i4 < ROW4; i4 += 256) {
        int c0 = i4 * 4;
        float4 v;
        v.x = (c0     == c1) ? v1 : ((c0     == c2) ? v2v : 0.0f);
        v.y = (c0 + 1 == c1) ? v1 : ((c0 + 1 == c2) ? v2v : 0.0f);
        v.z = (c0 + 2 == c1) ? v1 : ((c0 + 2 == c2) ? v2v : 0.0f);
        v.w = (c0 + 3 == c1) ? v1 : ((c0 + 3 == c2) ? v2v : 0.0f);
        row4[i4] = v;
    }
}

extern "C" void kernel_launch(void* const* d_in, const int* in_sizes, int n_in,
                              void* d_out, int out_size, void* d_ws, size_t ws_size,
                              hipStream_t stream) {
    const float* c  = (const float*)d_in[0];
    const float* k  = (const float*)d_in[1];
    const float* kp = (const float*)d_in[2];
    float* out = (float*)d_out;

    eigen_rows_kernel<<<2 * S + 1, 256, 0, stream>>>(c, k, kp, out);
}